// Round 1
// baseline (446.504 us; speedup 1.0000x reference)
//
#include <hip/hip_runtime.h>
#include <hip/hip_fp16.h>

// Problem constants
#define NH_   8
#define DQK_  256
#define DV_   64
#define NB_   8
#define TI_   16
#define TO_   16
#define HH_   32
#define WW_   32
#define FR_   (NB_*TI_)   // 128 frames
#define PX_   (HH_*WW_)   // 1024 pixels

typedef _Float16 f16x8 __attribute__((ext_vector_type(8)));
typedef _Float16 f16x4 __attribute__((ext_vector_type(4)));
typedef float    f32x4 __attribute__((ext_vector_type(4)));

// ---------------------------------------------------------------------------
// 1) v (fp32, [f][c][y][x]) -> v16t (f16, [f][y*32+x][c])  (NHWC for conv staging)
//    Reads coalesced; 2-B writes at 128-B stride merge in L2 (c-inner over iters).
__global__ void k_prep(const float* __restrict__ v, _Float16* __restrict__ v16t) {
    int f = blockIdx.x >> 1;
    int halfsel = blockIdx.x & 1;
    int t = threadIdx.x;
    const float* src = v + (size_t)f * DV_ * PX_;
    _Float16* dst = v16t + (size_t)f * PX_ * DV_;
    for (int idx = t; idx < DV_ * 512; idx += 256) {
        int c  = idx >> 9;
        int px = (idx & 511) + halfsel * 512;
        dst[px * DV_ + c] = (_Float16)src[c * PX_ + px];
    }
}

// ---------------------------------------------------------------------------
// 2) pq = q@Wq + bq, pk = k@Wk + bk   (fp32, [row=b*16+t][2048])
__global__ void k_proj(const float* __restrict__ q, const float* __restrict__ kk,
                       const float* __restrict__ Wq, const float* __restrict__ bq,
                       const float* __restrict__ Wk, const float* __restrict__ bk,
                       float* __restrict__ pq, float* __restrict__ pk) {
    __shared__ float qs[32][256];
    int mat = blockIdx.z;
    const float* X  = mat ? kk : q;
    const float* Wm = mat ? Wk : Wq;
    const float* bm = mat ? bk : bq;
    float* out = mat ? pk : pq;
    int t = threadIdx.x;
    int by = blockIdx.y;              // 32-row block
    for (int idx = t; idx < 32 * 256; idx += 256) {
        int r = idx >> 8, k2 = idx & 255;
        qs[r][k2] = X[(by * 32 + r) * 256 + k2];
    }
    __syncthreads();
    int nd = blockIdx.x * 64 + (t & 63);
    int jb = (t >> 6) * 8;
    float a[8];
    #pragma unroll
    for (int j = 0; j < 8; ++j) a[j] = 0.f;
    for (int k2 = 0; k2 < 256; ++k2) {
        float wv = Wm[k2 * 2048 + nd];
        #pragma unroll
        for (int j = 0; j < 8; ++j) a[j] += qs[jb + j][k2] * wv;
    }
    float bb = bm[nd];
    #pragma unroll
    for (int j = 0; j < 8; ++j)
        out[(size_t)(by * 32 + jb + j) * 2048 + nd] = a[j] + bb;
}

// ---------------------------------------------------------------------------
// 3) scores + mask + softmax -> wsm[b][n][o][i]  fp32
__global__ void k_scores(const float* __restrict__ pq, const float* __restrict__ pk,
                         const int* __restrict__ mask, float* __restrict__ wsm) {
    __shared__ float lq[16][256];
    __shared__ float lk[16][257];
    int b = blockIdx.x >> 3, n = blockIdx.x & 7;
    int t = threadIdx.x;
    for (int idx = t; idx < 4096; idx += 256) {
        int r = idx >> 8, dd = idx & 255;
        lq[r][dd] = pq[(size_t)(b * 16 + r) * 2048 + n * 256 + dd];
        lk[r][dd] = pk[(size_t)(b * 16 + r) * 2048 + n * 256 + dd];
    }
    __syncthreads();
    int o = t >> 4, i = t & 15;
    float s = 0.f;
    for (int dd = 0; dd < 256; ++dd) s += lq[o][dd] * lk[i][dd];
    s *= 0.0625f;  // 1/sqrt(256)
    if (mask[(b * 16 + o) * 16 + i] == 0) s = -1e10f;
    float mx = s;
    #pragma unroll
    for (int off = 1; off < 16; off <<= 1) mx = fmaxf(mx, __shfl_xor(mx, off, 16));
    float e = __expf(s - mx);
    float sum = e;
    #pragma unroll
    for (int off = 1; off < 16; off <<= 1) sum += __shfl_xor(sum, off, 16);
    wsm[((size_t)(b * 8 + n) * 16 + o) * 16 + i] = e / sum;
}

// ---------------------------------------------------------------------------
// 4) Fold Wp into Wv, pre-swizzled into MFMA A-fragment order:
//    Wf2[r][cg][oct16][lane][j]  (f16), oc = oct16*16 + (lane&15),
//    c = cg*32 + (lane>>4)*8 + j.  Wcomb[oc][c][r] = sum_c' Wp[d, n*64+c']*Wv[n*64+c', c, r]
__global__ void k_fold(const float* __restrict__ Wp, const float* __restrict__ Wv,
                       _Float16* __restrict__ Wf2) {
    int gid = blockIdx.x * 256 + threadIdx.x;   // < 36864
    int l = gid & 63;
    int oct16 = (gid >> 6) & 31;
    int cg = (gid >> 11) & 1;
    int r = gid >> 12;                           // 0..8
    int oc = oct16 * 16 + (l & 15);
    int n = oc >> 6, d = oc & 63;
    int cbase = cg * 32 + (l >> 4) * 8;
    float acc[8];
    #pragma unroll
    for (int j = 0; j < 8; ++j) acc[j] = 0.f;
    for (int c2 = 0; c2 < 64; ++c2) {
        float wp = Wp[d * 512 + n * 64 + c2];
        #pragma unroll
        for (int j = 0; j < 8; ++j)
            acc[j] += wp * Wv[((n * 64 + c2) * 64 + cbase + j) * 9 + r];
    }
    #pragma unroll
    for (int j = 0; j < 8; ++j) Wf2[(size_t)gid * 8 + j] = (_Float16)acc[j];
}

// bias_out[d] = bp[d] + sum_oc Wp[d][oc]*bv[oc]
__global__ void k_foldbias(const float* __restrict__ Wp, const float* __restrict__ bv,
                           const float* __restrict__ bp, float* __restrict__ bias_out) {
    int d = threadIdx.x;
    float acc = bp[d];
    for (int oc = 0; oc < 512; ++oc) acc += Wp[d * 512 + oc] * bv[oc];
    bias_out[d] = acc;
}

// ---------------------------------------------------------------------------
// 5) MFMA conv: per block (frame f, mblk of 128 oc, pxblk of 128 px = 4 rows)
//    Full K-panel (64ch x 6rows x 34cols halo slab) staged once in LDS,
//    then 18 k-steps (2 c-groups x 9 taps) of 16 MFMA, barrier-free.
__global__ __launch_bounds__(256) void k_conv(const _Float16* __restrict__ v16t,
                                              const _Float16* __restrict__ Wf2,
                                              _Float16* __restrict__ g) {
    __shared__ _Float16 slab[204 * 64];  // 26112 B; layout: pos(=yy*34+xx) rows of 128 B,
                                         // 8 x 16B slots (8 ch each), slot XOR-swizzled by pos&7
    int f = blockIdx.z, mblk = blockIdx.y, pxblk = blockIdx.x;
    int t = threadIdx.x;
    int l = t & 63, wm = t >> 6;

    const _Float16* vb = v16t + (size_t)f * PX_ * DV_;
    for (int task = t; task < 204 * 8; task += 256) {
        int pos = task >> 3, sl = task & 7;
        int yy = pos / 34;
        int xx = pos - yy * 34;
        int y = pxblk * 4 + yy - 1;
        int x = xx - 1;
        uint4 val = make_uint4(0u, 0u, 0u, 0u);
        if ((unsigned)y < 32u && (unsigned)x < 32u)
            val = *(const uint4*)(vb + (y * 32 + x) * 64 + sl * 8);
        int off = pos * 128 + ((sl ^ (pos & 7)) << 4);
        *(uint4*)((char*)slab + off) = val;
    }
    __syncthreads();

    int m = l & 15, kg = l >> 4;
    int pos0[8];
    #pragma unroll
    for (int nt = 0; nt < 8; ++nt) {
        int pxl = nt * 16 + m;
        pos0[nt] = (pxl >> 5) * 34 + (pxl & 31);
    }

    const f16x8* Wf8 = (const f16x8*)Wf2;
    f32x4 acc[2][8];
    #pragma unroll
    for (int mt = 0; mt < 2; ++mt)
        #pragma unroll
        for (int nt = 0; nt < 8; ++nt)
            acc[mt][nt] = (f32x4){0.f, 0.f, 0.f, 0.f};

    #pragma unroll
    for (int cg = 0; cg < 2; ++cg) {
        int slotb = (cg * 4 + kg) << 4;
        #pragma unroll
        for (int r = 0; r < 9; ++r) {
            int dd = (r / 3) * 34 + (r % 3);
            int abase = (r * 2 + cg) * 32 + mblk * 8 + wm * 2;
            f16x8 af0 = Wf8[(size_t)(abase + 0) * 64 + l];
            f16x8 af1 = Wf8[(size_t)(abase + 1) * 64 + l];
            f16x8 bf[8];
            #pragma unroll
            for (int nt = 0; nt < 8; ++nt) {
                int pos = pos0[nt] + dd;
                int off = pos * 128 + (slotb ^ ((pos & 7) << 4));
                bf[nt] = *(const f16x8*)((const char*)slab + off);
            }
            #pragma unroll
            for (int nt = 0; nt < 8; ++nt) {
                acc[0][nt] = __builtin_amdgcn_mfma_f32_16x16x32_f16(af0, bf[nt], acc[0][nt], 0, 0, 0);
                acc[1][nt] = __builtin_amdgcn_mfma_f32_16x16x32_f16(af1, bf[nt], acc[1][nt], 0, 0, 0);
            }
        }
    }

    // epilogue: g[f][oc][px] f16 (C frag: row=oc=(l>>4)*4+e, col=px=l&15)
    _Float16* gb = g + (size_t)f * 512 * 1024 + (size_t)pxblk * 128;
    #pragma unroll
    for (int mt = 0; mt < 2; ++mt) {
        int ocbase = (mblk * 8 + wm * 2 + mt) * 16 + kg * 4;
        #pragma unroll
        for (int nt = 0; nt < 8; ++nt) {
            int px = nt * 16 + m;
            #pragma unroll
            for (int e = 0; e < 4; ++e)
                gb[(size_t)(ocbase + e) * 1024 + px] = (_Float16)acc[mt][nt][e];
        }
    }
}

// ---------------------------------------------------------------------------
// 6) combine: out[b,o,d,px] = bias[d] + sum_{n,i} w[b,n,o,i] * g[b,i,n*64+d,px]
__global__ void k_comb(const _Float16* __restrict__ g, const float* __restrict__ wsm,
                       const float* __restrict__ bias_out, float* __restrict__ out) {
    __shared__ float wl[2048];   // [n][o][i]
    int d = blockIdx.y, b = blockIdx.z;
    int t = threadIdx.x;
    for (int idx = t; idx < 2048; idx += 256) wl[idx] = wsm[(size_t)b * 2048 + idx];
    __syncthreads();
    int px0 = t * 4;
    float acc[16][4];
    #pragma unroll
    for (int o = 0; o < 16; ++o)
        #pragma unroll
        for (int e = 0; e < 4; ++e) acc[o][e] = 0.f;

    for (int i = 0; i < 16; ++i) {
        #pragma unroll
        for (int n = 0; n < 8; ++n) {
            const _Float16* gp = g + ((size_t)((b * 16 + i) * 512 + n * 64 + d)) * 1024 + px0;
            f16x4 hv = *(const f16x4*)gp;
            float g0 = (float)hv[0], g1 = (float)hv[1], g2 = (float)hv[2], g3 = (float)hv[3];
            #pragma unroll
            for (int o = 0; o < 16; ++o) {
                float wv = wl[n * 256 + o * 16 + i];
                acc[o][0] += wv * g0;
                acc[o][1] += wv * g1;
                acc[o][2] += wv * g2;
                acc[o][3] += wv * g3;
            }
        }
    }
    float bo = bias_out[d];
    #pragma unroll
    for (int o = 0; o < 16; ++o) {
        float4 res = make_float4(acc[o][0] + bo, acc[o][1] + bo, acc[o][2] + bo, acc[o][3] + bo);
        *(float4*)(out + ((size_t)((b * 16 + o) * 64 + d)) * 1024 + px0) = res;
    }
}

// ---------------------------------------------------------------------------
extern "C" void kernel_launch(void* const* d_in, const int* in_sizes, int n_in,
                              void* d_out, int out_size, void* d_ws, size_t ws_size,
                              hipStream_t stream) {
    (void)in_sizes; (void)n_in; (void)out_size;
    const float* v  = (const float*)d_in[0];
    const float* kk = (const float*)d_in[1];
    const float* q  = (const float*)d_in[2];
    const int*   pm = (const int*)d_in[3];
    const float* Wq = (const float*)d_in[4];
    const float* bq = (const float*)d_in[5];
    const float* Wk = (const float*)d_in[6];
    const float* bk = (const float*)d_in[7];
    const float* Wv = (const float*)d_in[8];
    const float* bv = (const float*)d_in[9];
    const float* Wp = (const float*)d_in[10];
    const float* bp = (const float*)d_in[11];
    float* out = (float*)d_out;

    char* ws = (char*)d_ws;
    size_t o_v16t = 0;
    size_t o_g    = o_v16t + (size_t)FR_ * PX_ * DV_ * 2;          // 16 MB
    size_t o_wf2  = o_g    + (size_t)FR_ * 512 * PX_ * 2;          // +128 MB
    size_t o_pq   = o_wf2  + (size_t)9 * 2 * 32 * 64 * 8 * 2;      // +576 KB
    size_t o_pk   = o_pq   + (size_t)128 * 2048 * 4;               // +1 MB
    size_t o_wsm  = o_pk   + (size_t)128 * 2048 * 4;               // +1 MB
    size_t o_bias = o_wsm  + (size_t)NB_ * NH_ * TO_ * TI_ * 4;    // +64 KB
    size_t need   = o_bias + 256;
    if (ws_size < need) return;  // insufficient workspace; validation will flag

    _Float16* v16t = (_Float16*)(ws + o_v16t);
    _Float16* g    = (_Float16*)(ws + o_g);
    _Float16* Wf2  = (_Float16*)(ws + o_wf2);
    float* pq      = (float*)(ws + o_pq);
    float* pk      = (float*)(ws + o_pk);
    float* wsm     = (float*)(ws + o_wsm);
    float* bias    = (float*)(ws + o_bias);

    k_prep<<<dim3(256), dim3(256), 0, stream>>>(v, v16t);
    k_proj<<<dim3(32, 4, 2), dim3(256), 0, stream>>>(q, kk, Wq, bq, Wk, bk, pq, pk);
    k_scores<<<dim3(64), dim3(256), 0, stream>>>(pq, pk, pm, wsm);
    k_fold<<<dim3(144), dim3(256), 0, stream>>>(Wp, Wv, Wf2);
    k_foldbias<<<dim3(1), dim3(64), 0, stream>>>(Wp, bv, bp, bias);
    k_conv<<<dim3(8, 4, FR_), dim3(256), 0, stream>>>(v16t, Wf2, g);
    k_comb<<<dim3(1, 64, NB_), dim3(256), 0, stream>>>(g, wsm, bias, out);
}

// Round 2
// 321.687 us; speedup vs baseline: 1.3880x; 1.3880x over previous
//
#include <hip/hip_runtime.h>
#include <hip/hip_fp16.h>

// Problem constants
#define NH_   8
#define DQK_  256
#define DV_   64
#define NB_   8
#define TI_   16
#define TO_   16
#define HH_   32
#define WW_   32
#define FR_   (NB_*TI_)   // 128 frames
#define PX_   (HH_*WW_)   // 1024 pixels

typedef _Float16 f16x8 __attribute__((ext_vector_type(8)));
typedef _Float16 f16x4 __attribute__((ext_vector_type(4)));
typedef float    f32x4 __attribute__((ext_vector_type(4)));

// ---------------------------------------------------------------------------
// 1) v (fp32, [f][c][y][x]) -> v16t (f16, [f][y*32+x][c])  (NHWC for conv staging)
//    R1 rewrite: each lane owns ONE pixel -> reads 64 coalesced scalars
//    (lanes = consecutive px), then writes its full 128-B row with 8
//    back-to-back 16-B stores. Every 64-B line is fully covered by one lane
//    immediately -> no partial-line eviction (R0: 443 MB WRITE_SIZE, 27x amp).
__global__ __launch_bounds__(256) void k_prep(const float* __restrict__ v,
                                              _Float16* __restrict__ v16t) {
    int blk = blockIdx.x;            // 512 blocks: f = blk>>2, quarter = blk&3
    int f = blk >> 2;
    int px = ((blk & 3) << 8) + threadIdx.x;
    const float* src = v + (size_t)f * DV_ * PX_;
    _Float16* dst = v16t + (size_t)f * PX_ * DV_ + (size_t)px * DV_;
    f16x8 buf[8];
    #pragma unroll
    for (int cg = 0; cg < 8; ++cg) {
        #pragma unroll
        for (int j = 0; j < 8; ++j)
            buf[cg][j] = (_Float16)src[(cg * 8 + j) * PX_ + px];
    }
    #pragma unroll
    for (int cg = 0; cg < 8; ++cg)
        *(f16x8*)(dst + cg * 8) = buf[cg];
}

// ---------------------------------------------------------------------------
// 2) pq = q@Wq + bq, pk = k@Wk + bk   (fp32, [row=b*16+t][2048])
__global__ void k_proj(const float* __restrict__ q, const float* __restrict__ kk,
                       const float* __restrict__ Wq, const float* __restrict__ bq,
                       const float* __restrict__ Wk, const float* __restrict__ bk,
                       float* __restrict__ pq, float* __restrict__ pk) {
    __shared__ float qs[32][256];
    int mat = blockIdx.z;
    const float* X  = mat ? kk : q;
    const float* Wm = mat ? Wk : Wq;
    const float* bm = mat ? bk : bq;
    float* out = mat ? pk : pq;
    int t = threadIdx.x;
    int by = blockIdx.y;              // 32-row block
    for (int idx = t; idx < 32 * 256; idx += 256) {
        int r = idx >> 8, k2 = idx & 255;
        qs[r][k2] = X[(by * 32 + r) * 256 + k2];
    }
    __syncthreads();
    int nd = blockIdx.x * 64 + (t & 63);
    int jb = (t >> 6) * 8;
    float a[8];
    #pragma unroll
    for (int j = 0; j < 8; ++j) a[j] = 0.f;
    for (int k2 = 0; k2 < 256; ++k2) {
        float wv = Wm[k2 * 2048 + nd];
        #pragma unroll
        for (int j = 0; j < 8; ++j) a[j] += qs[jb + j][k2] * wv;
    }
    float bb = bm[nd];
    #pragma unroll
    for (int j = 0; j < 8; ++j)
        out[(size_t)(by * 32 + jb + j) * 2048 + nd] = a[j] + bb;
}

// ---------------------------------------------------------------------------
// 3) scores + mask + softmax -> wsm[b][n][o][i]  fp32
__global__ void k_scores(const float* __restrict__ pq, const float* __restrict__ pk,
                         const int* __restrict__ mask, float* __restrict__ wsm) {
    __shared__ float lq[16][256];
    __shared__ float lk[16][257];
    int b = blockIdx.x >> 3, n = blockIdx.x & 7;
    int t = threadIdx.x;
    for (int idx = t; idx < 4096; idx += 256) {
        int r = idx >> 8, dd = idx & 255;
        lq[r][dd] = pq[(size_t)(b * 16 + r) * 2048 + n * 256 + dd];
        lk[r][dd] = pk[(size_t)(b * 16 + r) * 2048 + n * 256 + dd];
    }
    __syncthreads();
    int o = t >> 4, i = t & 15;
    float s = 0.f;
    for (int dd = 0; dd < 256; ++dd) s += lq[o][dd] * lk[i][dd];
    s *= 0.0625f;  // 1/sqrt(256)
    if (mask[(b * 16 + o) * 16 + i] == 0) s = -1e10f;
    float mx = s;
    #pragma unroll
    for (int off = 1; off < 16; off <<= 1) mx = fmaxf(mx, __shfl_xor(mx, off, 16));
    float e = __expf(s - mx);
    float sum = e;
    #pragma unroll
    for (int off = 1; off < 16; off <<= 1) sum += __shfl_xor(sum, off, 16);
    wsm[((size_t)(b * 8 + n) * 16 + o) * 16 + i] = e / sum;
}

// ---------------------------------------------------------------------------
// 4) Fold Wp into Wv, pre-swizzled into MFMA A-fragment order:
//    Wf2[r][cg][oct16][lane][j]  (f16), oc = oct16*16 + (lane&15),
//    c = cg*32 + (lane>>4)*8 + j.  Wcomb[oc][c][r] = sum_c' Wp[d, n*64+c']*Wv[n*64+c', c, r]
__global__ void k_fold(const float* __restrict__ Wp, const float* __restrict__ Wv,
                       _Float16* __restrict__ Wf2) {
    int gid = blockIdx.x * 256 + threadIdx.x;   // < 36864
    int l = gid & 63;
    int oct16 = (gid >> 6) & 31;
    int cg = (gid >> 11) & 1;
    int r = gid >> 12;                           // 0..8
    int oc = oct16 * 16 + (l & 15);
    int n = oc >> 6, d = oc & 63;
    int cbase = cg * 32 + (l >> 4) * 8;
    float acc[8];
    #pragma unroll
    for (int j = 0; j < 8; ++j) acc[j] = 0.f;
    for (int c2 = 0; c2 < 64; ++c2) {
        float wp = Wp[d * 512 + n * 64 + c2];
        #pragma unroll
        for (int j = 0; j < 8; ++j)
            acc[j] += wp * Wv[((n * 64 + c2) * 64 + cbase + j) * 9 + r];
    }
    #pragma unroll
    for (int j = 0; j < 8; ++j) Wf2[(size_t)gid * 8 + j] = (_Float16)acc[j];
}

// bias_out[d] = bp[d] + sum_oc Wp[d][oc]*bv[oc]
__global__ void k_foldbias(const float* __restrict__ Wp, const float* __restrict__ bv,
                           const float* __restrict__ bp, float* __restrict__ bias_out) {
    int d = threadIdx.x;
    float acc = bp[d];
    for (int oc = 0; oc < 512; ++oc) acc += Wp[d * 512 + oc] * bv[oc];
    bias_out[d] = acc;
}

// ---------------------------------------------------------------------------
// 5) MFMA conv: per block (frame f, mblk of 128 oc, pxblk of 128 px = 4 rows)
//    Full K-panel (64ch x 6rows x 34cols halo slab) staged once in LDS,
//    then 18 k-steps (2 c-groups x 9 taps) of 16 MFMA, barrier-free.
__global__ __launch_bounds__(256) void k_conv(const _Float16* __restrict__ v16t,
                                              const _Float16* __restrict__ Wf2,
                                              _Float16* __restrict__ g) {
    __shared__ _Float16 slab[204 * 64];  // 26112 B; layout: pos(=yy*34+xx) rows of 128 B,
                                         // 8 x 16B slots (8 ch each), slot XOR-swizzled by pos&7
    int f = blockIdx.z, mblk = blockIdx.y, pxblk = blockIdx.x;
    int t = threadIdx.x;
    int l = t & 63, wm = t >> 6;

    const _Float16* vb = v16t + (size_t)f * PX_ * DV_;
    for (int task = t; task < 204 * 8; task += 256) {
        int pos = task >> 3, sl = task & 7;
        int yy = pos / 34;
        int xx = pos - yy * 34;
        int y = pxblk * 4 + yy - 1;
        int x = xx - 1;
        uint4 val = make_uint4(0u, 0u, 0u, 0u);
        if ((unsigned)y < 32u && (unsigned)x < 32u)
            val = *(const uint4*)(vb + (y * 32 + x) * 64 + sl * 8);
        int off = pos * 128 + ((sl ^ (pos & 7)) << 4);
        *(uint4*)((char*)slab + off) = val;
    }
    __syncthreads();

    int m = l & 15, kg = l >> 4;
    int pos0[8];
    #pragma unroll
    for (int nt = 0; nt < 8; ++nt) {
        int pxl = nt * 16 + m;
        pos0[nt] = (pxl >> 5) * 34 + (pxl & 31);
    }

    const f16x8* Wf8 = (const f16x8*)Wf2;
    f32x4 acc[2][8];
    #pragma unroll
    for (int mt = 0; mt < 2; ++mt)
        #pragma unroll
        for (int nt = 0; nt < 8; ++nt)
            acc[mt][nt] = (f32x4){0.f, 0.f, 0.f, 0.f};

    #pragma unroll
    for (int cg = 0; cg < 2; ++cg) {
        int slotb = (cg * 4 + kg) << 4;
        #pragma unroll
        for (int r = 0; r < 9; ++r) {
            int dd = (r / 3) * 34 + (r % 3);
            int abase = (r * 2 + cg) * 32 + mblk * 8 + wm * 2;
            f16x8 af0 = Wf8[(size_t)(abase + 0) * 64 + l];
            f16x8 af1 = Wf8[(size_t)(abase + 1) * 64 + l];
            f16x8 bf[8];
            #pragma unroll
            for (int nt = 0; nt < 8; ++nt) {
                int pos = pos0[nt] + dd;
                int off = pos * 128 + (slotb ^ ((pos & 7) << 4));
                bf[nt] = *(const f16x8*)((const char*)slab + off);
            }
            #pragma unroll
            for (int nt = 0; nt < 8; ++nt) {
                acc[0][nt] = __builtin_amdgcn_mfma_f32_16x16x32_f16(af0, bf[nt], acc[0][nt], 0, 0, 0);
                acc[1][nt] = __builtin_amdgcn_mfma_f32_16x16x32_f16(af1, bf[nt], acc[1][nt], 0, 0, 0);
            }
        }
    }

    // epilogue: g[f][oc][px] f16 (C frag: row=oc=(l>>4)*4+e, col=px=l&15)
    _Float16* gb = g + (size_t)f * 512 * 1024 + (size_t)pxblk * 128;
    #pragma unroll
    for (int mt = 0; mt < 2; ++mt) {
        int ocbase = (mblk * 8 + wm * 2 + mt) * 16 + kg * 4;
        #pragma unroll
        for (int nt = 0; nt < 8; ++nt) {
            int px = nt * 16 + m;
            #pragma unroll
            for (int e = 0; e < 4; ++e)
                gb[(size_t)(ocbase + e) * 1024 + px] = (_Float16)acc[mt][nt][e];
        }
    }
}

// ---------------------------------------------------------------------------
// 6) combine: out[b,o,d,px] = bias[d] + sum_{n,i} w[b,n,o,i] * g[b,i,n*64+d,px]
__global__ void k_comb(const _Float16* __restrict__ g, const float* __restrict__ wsm,
                       const float* __restrict__ bias_out, float* __restrict__ out) {
    __shared__ float wl[2048];   // [n][o][i]
    int d = blockIdx.y, b = blockIdx.z;
    int t = threadIdx.x;
    for (int idx = t; idx < 2048; idx += 256) wl[idx] = wsm[(size_t)b * 2048 + idx];
    __syncthreads();
    int px0 = t * 4;
    float acc[16][4];
    #pragma unroll
    for (int o = 0; o < 16; ++o)
        #pragma unroll
        for (int e = 0; e < 4; ++e) acc[o][e] = 0.f;

    for (int i = 0; i < 16; ++i) {
        #pragma unroll
        for (int n = 0; n < 8; ++n) {
            const _Float16* gp = g + ((size_t)((b * 16 + i) * 512 + n * 64 + d)) * 1024 + px0;
            f16x4 hv = *(const f16x4*)gp;
            float g0 = (float)hv[0], g1 = (float)hv[1], g2 = (float)hv[2], g3 = (float)hv[3];
            #pragma unroll
            for (int o = 0; o < 16; ++o) {
                float wv = wl[n * 256 + o * 16 + i];
                acc[o][0] += wv * g0;
                acc[o][1] += wv * g1;
                acc[o][2] += wv * g2;
                acc[o][3] += wv * g3;
            }
        }
    }
    float bo = bias_out[d];
    #pragma unroll
    for (int o = 0; o < 16; ++o) {
        float4 res = make_float4(acc[o][0] + bo, acc[o][1] + bo, acc[o][2] + bo, acc[o][3] + bo);
        *(float4*)(out + ((size_t)((b * 16 + o) * 64 + d)) * 1024 + px0) = res;
    }
}

// ---------------------------------------------------------------------------
extern "C" void kernel_launch(void* const* d_in, const int* in_sizes, int n_in,
                              void* d_out, int out_size, void* d_ws, size_t ws_size,
                              hipStream_t stream) {
    (void)in_sizes; (void)n_in; (void)out_size;
    const float* v  = (const float*)d_in[0];
    const float* kk = (const float*)d_in[1];
    const float* q  = (const float*)d_in[2];
    const int*   pm = (const int*)d_in[3];
    const float* Wq = (const float*)d_in[4];
    const float* bq = (const float*)d_in[5];
    const float* Wk = (const float*)d_in[6];
    const float* bk = (const float*)d_in[7];
    const float* Wv = (const float*)d_in[8];
    const float* bv = (const float*)d_in[9];
    const float* Wp = (const float*)d_in[10];
    const float* bp = (const float*)d_in[11];
    float* out = (float*)d_out;

    char* ws = (char*)d_ws;
    size_t o_v16t = 0;
    size_t o_g    = o_v16t + (size_t)FR_ * PX_ * DV_ * 2;          // 16 MB
    size_t o_wf2  = o_g    + (size_t)FR_ * 512 * PX_ * 2;          // +128 MB
    size_t o_pq   = o_wf2  + (size_t)9 * 2 * 32 * 64 * 8 * 2;      // +576 KB
    size_t o_pk   = o_pq   + (size_t)128 * 2048 * 4;               // +1 MB
    size_t o_wsm  = o_pk   + (size_t)128 * 2048 * 4;               // +1 MB
    size_t o_bias = o_wsm  + (size_t)NB_ * NH_ * TO_ * TI_ * 4;    // +64 KB
    size_t need   = o_bias + 256;
    if (ws_size < need) return;  // insufficient workspace; validation will flag

    _Float16* v16t = (_Float16*)(ws + o_v16t);
    _Float16* g    = (_Float16*)(ws + o_g);
    _Float16* Wf2  = (_Float16*)(ws + o_wf2);
    float* pq      = (float*)(ws + o_pq);
    float* pk      = (float*)(ws + o_pk);
    float* wsm     = (float*)(ws + o_wsm);
    float* bias    = (float*)(ws + o_bias);

    k_prep<<<dim3(512), dim3(256), 0, stream>>>(v, v16t);
    k_proj<<<dim3(32, 4, 2), dim3(256), 0, stream>>>(q, kk, Wq, bq, Wk, bk, pq, pk);
    k_scores<<<dim3(64), dim3(256), 0, stream>>>(pq, pk, pm, wsm);
    k_fold<<<dim3(144), dim3(256), 0, stream>>>(Wp, Wv, Wf2);
    k_foldbias<<<dim3(1), dim3(64), 0, stream>>>(Wp, bv, bp, bias);
    k_conv<<<dim3(8, 4, FR_), dim3(256), 0, stream>>>(v16t, Wf2, g);
    k_comb<<<dim3(1, 64, NB_), dim3(256), 0, stream>>>(g, wsm, bias, out);
}